// Round 1
// baseline (11264.540 us; speedup 1.0000x reference)
//
#include <hip/hip_runtime.h>
#include <cstdint>
#include <cstddef>

typedef unsigned short u16;
typedef unsigned int u32;
typedef unsigned long long u64;
typedef short bf16x8 __attribute__((ext_vector_type(8)));
typedef float f32x4 __attribute__((ext_vector_type(4)));
typedef unsigned short u16x4 __attribute__((ext_vector_type(4)));

#define T_LEN 1200

// workspace byte offsets (all 256-aligned). Total ~48.0 MB.
#define O_X     0ull           // x bf16: 38400*512*2        = 39,321,600
#define O_WIH   39321600ull    // W_ih cat bf16: 4096*512*2  =  4,194,304
#define O_WHH   43515904ull    // W_hh cat bf16: 4096*512*2  =  4,194,304
#define O_BIAS  47710208ull    // bias cat f32: 4096*4       =     16,384
#define O_HBUF  47726592ull    // tagged h dwords: 2 par * 2 dir * 32*512 * 4B = 262,144
#define WS_NEED 47988736ull

#define HO 19660800ull   // h_n offset in d_out (floats)
#define CO 19693568ull   // c_n offset in d_out (floats)

#define HROW 516         // padded LDS row stride (u16 elems): +4 pad -> 2-way banks (free)

__device__ __forceinline__ u16 f2bf(float f) {
  union { float f; unsigned u; } v; v.f = f;
  unsigned r = v.u + 0x7FFFu + ((v.u >> 16) & 1u);
  return (u16)(r >> 16);
}
__device__ __forceinline__ float sigm(float x) { return 1.f / (1.f + __expf(-x)); }
__device__ __forceinline__ float tanh_s(float x) {
  float ax = fabsf(x);
  float e = __expf(-2.f * ax);          // in (0,1], no overflow
  float t = (1.f - e) / (1.f + e);
  return x < 0.f ? -t : t;
}

// device-coherent 8B load / 4B store (global_load/store with sc0 sc1, LLC-direct)
__device__ __forceinline__ u64 ld_dev64(const u32* p) {
  return __hip_atomic_load((const u64*)p, __ATOMIC_RELAXED, __HIP_MEMORY_SCOPE_AGENT);
}
__device__ __forceinline__ void st_dev32(u32* p, unsigned v) {
  __hip_atomic_store(p, v, __ATOMIC_RELAXED, __HIP_MEMORY_SCOPE_AGENT);
}

// ---------------- cast x (f32 -> bf16), 4 elems/thread ----------------
__global__ __launch_bounds__(256) void cast_x_k(const float4* __restrict__ x,
                                                u16* __restrict__ xb) {
  int i = blockIdx.x * 256 + threadIdx.x;   // 4,915,200 threads
  float4 v = x[i];
  u16x4 o;
  o.x = f2bf(v.x); o.y = f2bf(v.y); o.z = f2bf(v.z); o.w = f2bf(v.w);
  *(u16x4*)(xb + (size_t)i * 4) = o;
}

// ---------------- concat + cast weights, fold biases ----------------
__global__ __launch_bounds__(256) void prep_w_k(
    const float* __restrict__ wih_f, const float* __restrict__ whh_f,
    const float* __restrict__ bih_f, const float* __restrict__ bhh_f,
    const float* __restrict__ wih_b, const float* __restrict__ whh_b,
    const float* __restrict__ bih_b, const float* __restrict__ bhh_b,
    u16* __restrict__ Wih, u16* __restrict__ Whh, float* __restrict__ bias) {
  int tid = blockIdx.x * 256 + threadIdx.x;   // 0 .. 4096*512-1
  int g = tid >> 9;
  float vi, vh;
  if (g < 2048) { vi = wih_f[tid]; vh = whh_f[tid]; }
  else { int t2 = tid - (2048 * 512); vi = wih_b[t2]; vh = whh_b[t2]; }
  Wih[tid] = f2bf(vi);
  Whh[tid] = f2bf(vh);
  if ((tid & 511) == 0) {
    bias[g] = (g < 2048) ? (bih_f[g] + bhh_f[g]) : (bih_b[g - 2048] + bhh_b[g - 2048]);
  }
}

// ---------------- persistent bidirectional LSTM recurrence ----------------
// 64 blocks: dir = bx>>5, slice = bx&31 (16 h-cols each). W_ih/W_hh slices
// live in registers as MFMA B-fragments for all 1200 steps.
//
// R7 change: SELF-SYNCHRONIZING h exchange. Each h element is published as a
// 32-bit word: (bf16(h) << 16) | step_tag. Consumers poll the payload words
// directly until all 64 words/thread carry tag t — this collapses the old
// {store-ack drain, flag store, flag poll, data load} chain (3-4 serial LLC
// round trips/step) into ONE. The parity double-buffer guarantees tag-t data
// is only overwritten with tag t+2 after every block consumed tag t, so
// per-word tagging is race-free (each dword = one 32-bit store, no tearing).
// Barriers per step: 4 -> 2; h/c state moved from LDS to registers; no flag
// array; out-atomics' acks drain under the next step's poll, not a barrier.
__global__ __launch_bounds__(256, 1) void lstm_rec(const u16* __restrict__ X,
                                                   const u16* __restrict__ Wih,
                                                   const u16* __restrict__ Whh,
                                                   const float* __restrict__ bias,
                                                   const int* __restrict__ lengths,
                                                   u32* __restrict__ hbuf,
                                                   float* __restrict__ out) {
  const int tid = threadIdx.x, lane = tid & 63, wid = tid >> 6;
  const int bx = blockIdx.x;
  const int dir = bx >> 5, slice = bx & 31, c0 = slice * 16;
  const int quad = lane >> 4, l15 = lane & 15;

  __shared__ alignas(16) u16 h_l[32 * HROW];   // staged h(t), padded rows
  __shared__ float pre[4][32][16];
  __shared__ int len_s[32];

  if (tid < 32) len_s[tid] = lengths[tid];

  // B-fragments (resident whole loop): wave `wid` owns gate `wid` (i/f/g/o),
  // 16 gate cols. B[k][n] layout: n = l15, k = ks*32 + quad*8 + j.
  bf16x8 bh[16], bxw[16];
  {
    const size_t wrow = (size_t)(dir * 2048 + wid * 512 + c0 + l15) * 512 + quad * 8;
#pragma unroll
    for (int ks = 0; ks < 16; ++ks) {
      bh[ks]  = *(const bf16x8*)(Whh + wrow + (size_t)ks * 32);
      bxw[ks] = *(const bf16x8*)(Wih + wrow + (size_t)ks * 32);
    }
  }
  __syncthreads();   // len_s ready; h_l/pre not yet used

  const int b0 = tid >> 4, colv = tid & 15, b1 = b0 + 16;
  const int hcol = c0 + colv;
  const float bi  = bias[dir * 2048 + 0 * 512 + hcol];
  const float bfv = bias[dir * 2048 + 1 * 512 + hcol];
  const float bg  = bias[dir * 2048 + 2 * 512 + hcol];
  const float bo  = bias[dir * 2048 + 3 * 512 + hcol];

  // per-thread recurrent state (this thread exclusively owns (b0,hcol),(b1,hcol))
  float hreg0 = 0.f, hreg1 = 0.f, creg0 = 0.f, creg1 = 0.f;
  const int len0 = len_s[b0], len1 = len_s[b1];
  const int lena = len_s[l15], lenb = len_s[16 + l15];

  for (int t = 0; t < T_LEN; ++t) {
    u32* cur = hbuf + (size_t)(((t & 1) * 2 + dir) * 16384);
    u32* nxt = hbuf + (size_t)((((t + 1) & 1) * 2 + dir) * 16384);

    // ---- x loads first: h-independent, L2-cached ----
    int tta = (dir == 0) ? t : (lena - 1 - t);  if (tta < 0) tta = 0;
    int ttb = (dir == 0) ? t : (lenb - 1 - t);  if (ttb < 0) ttb = 0;
    const u16* xrow0 = X + ((size_t)tta * 32 + l15) * 512 + quad * 8;
    const u16* xrow1 = X + ((size_t)ttb * 32 + 16 + l15) * 512 + quad * 8;
    bf16x8 ax0[16], ax1[16];
#pragma unroll
    for (int ks = 0; ks < 16; ++ks) {
      ax0[ks] = *(const bf16x8*)(xrow0 + (size_t)ks * 32);
      ax1[ks] = *(const bf16x8*)(xrow1 + (size_t)ks * 32);
    }

    // ---- issue staged h loads (64 dwords/thread, coalesced 8B LLC loads) ----
    u64 stg[32];
#pragma unroll
    for (int j = 0; j < 32; ++j)
      stg[j] = ld_dev64(cur + j * 512 + tid * 2);

    // x-part MFMAs overlap the staging loads' LLC latency (no dependence)
    f32x4 a0 = {0.f,0.f,0.f,0.f}, a1 = {0.f,0.f,0.f,0.f};
#pragma unroll
    for (int ks = 0; ks < 16; ++ks) {
      a0 = __builtin_amdgcn_mfma_f32_16x16x32_bf16(ax0[ks], bxw[ks], a0, 0, 0, 0);
      a1 = __builtin_amdgcn_mfma_f32_16x16x32_bf16(ax1[ks], bxw[ks], a1, 0, 0, 0);
    }

    // ---- poll: retry until every word carries tag t (h(t) fully published) ----
    const u64 e2 = ((u64)(u32)t << 32) | (u32)t;
    for (;;) {
      u64 bad = 0;
#pragma unroll
      for (int j = 0; j < 32; ++j) bad |= (stg[j] ^ e2);
      if ((bad & 0x0000FFFF0000FFFFull) == 0) break;
#pragma unroll
      for (int j = 0; j < 32; ++j)
        stg[j] = ld_dev64(cur + j * 512 + tid * 2);
    }

    // ---- unpack payload into padded LDS image (row j = batch j) ----
#pragma unroll
    for (int j = 0; j < 32; ++j) {
      u32 d0 = (u32)stg[j], d1 = (u32)(stg[j] >> 32);
      *(u32*)&h_l[j * HROW + tid * 2] = (d0 >> 16) | (d1 & 0xFFFF0000u);
    }
    __syncthreads();   // B1: h image ready

    // ---- h-part MFMAs from LDS fragments ----
    const u16* hl0 = h_l + (size_t)l15 * HROW + quad * 8;
    const u16* hl1 = h_l + (size_t)(16 + l15) * HROW + quad * 8;
#pragma unroll
    for (int ks = 0; ks < 16; ++ks) {
      bf16x8 f0 = *(const bf16x8*)(hl0 + ks * 32);
      bf16x8 f1 = *(const bf16x8*)(hl1 + ks * 32);
      a0 = __builtin_amdgcn_mfma_f32_16x16x32_bf16(f0, bh[ks], a0, 0, 0, 0);
      a1 = __builtin_amdgcn_mfma_f32_16x16x32_bf16(f1, bh[ks], a1, 0, 0, 0);
    }
    // C/D layout: row (=batch in tile) = quad*4+r, col (=gate col) = l15
#pragma unroll
    for (int r = 0; r < 4; ++r) {
      pre[wid][quad * 4 + r][l15]      = a0[r];
      pre[wid][16 + quad * 4 + r][l15] = a1[r];
    }
    __syncthreads();   // B2: pre ready (also fences h_l reads vs next-iter writes)

    // ---- cell update (per-thread state in registers) ----
    int tt0 = (dir == 0) ? t : (len0 - 1 - t);
    int tt1 = (dir == 0) ? t : (len1 - 1 - t);
    bool m0 = (dir == 0) ? (t < len0) : (tt0 >= 0);
    bool m1 = (dir == 0) ? (t < len1) : (tt1 >= 0);
    if (tt0 < 0) tt0 = 0;
    if (tt1 < 0) tt1 = 0;

    float hn0 = 0.f, hn1 = 0.f;
    if (m0) {
      float gi = pre[0][b0][colv] + bi,  gf = pre[1][b0][colv] + bfv;
      float gg = pre[2][b0][colv] + bg,  go = pre[3][b0][colv] + bo;
      float cn = sigm(gf) * creg0 + sigm(gi) * tanh_s(gg);
      hn0 = sigm(go) * tanh_s(cn);
      creg0 = cn; hreg0 = hn0;
    }
    if (m1) {
      float gi = pre[0][b1][colv] + bi,  gf = pre[1][b1][colv] + bfv;
      float gg = pre[2][b1][colv] + bg,  go = pre[3][b1][colv] + bo;
      float cn = sigm(gf) * creg1 + sigm(gi) * tanh_s(gg);
      hn1 = sigm(go) * tanh_s(cn);
      creg1 = cn; hreg1 = hn1;
    }

    // ---- publish tagged h(t+1): fire-and-forget, no drain, no flag ----
    const u32 tag = (u32)(t + 1);
    st_dev32(nxt + (size_t)b0 * 512 + hcol, ((u32)f2bf(hreg0) << 16) | tag);
    st_dev32(nxt + (size_t)b1 * 512 + hcol, ((u32)f2bf(hreg1) << 16) | tag);

    // out accumulation fully off the critical path (acks drain under next poll)
    if (m0) atomicAdd(out + (size_t)(tt0 * 32 + b0) * 512 + hcol, hn0);
    if (m1) atomicAdd(out + (size_t)(tt1 * 32 + b1) * 512 + hcol, hn1);
  }

  // finals: h_n (2,B,H), c_n (2,B,H)
  out[HO + (size_t)dir * 16384 + (size_t)b0 * 512 + hcol] = hreg0;
  out[HO + (size_t)dir * 16384 + (size_t)b1 * 512 + hcol] = hreg1;
  out[CO + (size_t)dir * 16384 + (size_t)b0 * 512 + hcol] = creg0;
  out[CO + (size_t)dir * 16384 + (size_t)b1 * 512 + hcol] = creg1;
}

extern "C" void kernel_launch(void* const* d_in, const int* in_sizes, int n_in,
                              void* d_out, int out_size, void* d_ws, size_t ws_size,
                              hipStream_t stream) {
  const float* x     = (const float*)d_in[0];
  const int*   lens  = (const int*)d_in[1];
  const float* wih_f = (const float*)d_in[2];
  const float* whh_f = (const float*)d_in[3];
  const float* bih_f = (const float*)d_in[4];
  const float* bhh_f = (const float*)d_in[5];
  const float* wih_b = (const float*)d_in[6];
  const float* whh_b = (const float*)d_in[7];
  const float* bih_b = (const float*)d_in[8];
  const float* bhh_b = (const float*)d_in[9];
  float* out = (float*)d_out;
  char* ws = (char*)d_ws;

  u16*   xb   = (u16*)(ws + O_X);
  u16*   Wih  = (u16*)(ws + O_WIH);
  u16*   Whh  = (u16*)(ws + O_WHH);
  float* bias = (float*)(ws + O_BIAS);
  u32*   hbuf = (u32*)(ws + O_HBUF);

  hipMemsetAsync(hbuf, 0, 262144, stream);                 // tag 0 == h(0) == 0
  hipMemsetAsync(d_out, 0, (size_t)out_size * 4, stream);  // out accumulated via atomics

  cast_x_k<<<19200, 256, 0, stream>>>((const float4*)x, xb);
  prep_w_k<<<8192, 256, 0, stream>>>(wih_f, whh_f, bih_f, bhh_f,
                                     wih_b, whh_b, bih_b, bhh_b, Wih, Whh, bias);
  lstm_rec<<<64, 256, 0, stream>>>(xb, Wih, Whh, bias, lens, hbuf, out);
}